// Round 6
// baseline (234.270 us; speedup 1.0000x reference)
//
#include <hip/hip_runtime.h>

#define N_NODES 50000
#define N_EDGES 800000
#define CAP 48        // max realized degree ~38 (Binomial(800k,1/50k)); guarded anyway
#define NBUCK 391     // dst>>7 buckets of 128 nodes
#define NBK 98        // edge-chunk blocks for hist/place
#define EPB 8192      // edges per block (NBK*EPB >= N_EDGES)

typedef __bf16 bf16_t;
typedef bf16_t bf16x8 __attribute__((ext_vector_type(8)));
typedef float f32x16 __attribute__((ext_vector_type(16)));

union Frag { float4 f4; bf16x8 h; };
union Pack8 { ushort u[8]; float4 f4; };

__device__ __forceinline__ ushort f2bf(float f) {   // RNE, inputs never NaN/Inf
    unsigned u = __float_as_uint(f);
    return (ushort)((u + 0x7fffu + ((u >> 16) & 1u)) >> 16);
}
__device__ __forceinline__ float bf2f(unsigned bits) {
    return __uint_as_float(bits << 16);
}

// ---------------------------------------------------------------------------
// Fused prep: detect int64-vs-int32 edge_index (wave 0: if int64, odd 32-bit
// words are zero high-halves); x f32 -> bf16 pairs; pack B fragments.
__global__ __launch_bounds__(256) void prep_kernel(
        const int* __restrict__ idx, int* __restrict__ flag,
        const float2* __restrict__ X, uint* __restrict__ Xb,
        const float* __restrict__ W1l, const float* __restrict__ W1r,
        const float* __restrict__ W2l, const float* __restrict__ W2r,
        ushort* __restrict__ Bp) {
    int i = blockIdx.x * 256 + threadIdx.x;
    if (blockIdx.x == 0 && threadIdx.x < 64) {
        int v = idx[2 * threadIdx.x + 1];
        unsigned long long b = __ballot(v == 0);
        if (threadIdx.x == 0) *flag = (b == 0xFFFFFFFFFFFFFFFFull) ? 1 : 0;
    }
    if (i < N_NODES * 64) {
        float2 v = X[i];
        Xb[i] = ((uint)f2bf(v.y) << 16) | (uint)f2bf(v.x);
    }
    if (i < 8192) {
        int layer = i >> 12;
        int rec   = i & 4095;
        int t = rec >> 10;
        int s = (rec >> 6) & 15;
        int l = rec & 63;
        const float* Wl = layer ? W2l : W1l;
        const float* Wr = layer ? W2r : W1r;
        int n = t * 32 + (l & 31);
        int kb = s * 16 + (l >> 5) * 8;
        Pack8 o;
#pragma unroll
        for (int j = 0; j < 8; ++j) {
            int k = kb + j;
            float v = (k < 128) ? Wl[k * 128 + n] : Wr[(k - 128) * 128 + n];
            o.u[j] = f2bf(v);
        }
        *(float4*)(Bp + (size_t)i * 8) = o.f4;
    }
}

// ---------------------------------------------------------------------------
// Pass A: exact per-(bucket,block) histogram via LDS.
__global__ __launch_bounds__(1024) void hist_kernel(
        const int* __restrict__ idx, const int* __restrict__ flag,
        int* __restrict__ counts) {
    __shared__ int h[NBUCK];
    for (int i = threadIdx.x; i < NBUCK; i += 1024) h[i] = 0;
    __syncthreads();
    const int f = *flag;
    const int base = blockIdx.x * EPB;
    const int end = min(base + EPB, N_EDGES);
    for (int e = base + threadIdx.x; e < end; e += 1024) {
        int dst = f ? idx[2 * N_EDGES + 2 * e] : idx[N_EDGES + e];
        atomicAdd(&h[dst >> 7], 1);
    }
    __syncthreads();
    for (int b = threadIdx.x; b < NBUCK; b += 1024)
        counts[b * NBK + blockIdx.x] = h[b];
}

// Pass B: one block. Bucket totals -> exclusive bucket starts -> exact
// per-(bucket,block) offsets (in-place over counts). Serial-in-bucket (98),
// parallel-over-buckets (391 threads of 512).
__global__ __launch_bounds__(512) void scan_kernel(int* __restrict__ counts,
                                                   int* __restrict__ bstart) {
    __shared__ int tot[512];
    const int b = threadIdx.x;
    int s = 0;
    if (b < NBUCK)
        for (int j = 0; j < NBK; ++j) s += counts[b * NBK + j];
    tot[b] = (b < NBUCK) ? s : 0;
    __syncthreads();
    int v = tot[b];
    for (int off = 1; off < 512; off <<= 1) {
        int t = (b >= off) ? tot[b - off] : 0;
        __syncthreads();
        tot[b] += t;
        __syncthreads();
    }
    const int start = tot[b] - v;     // exclusive
    if (b < NBUCK) {
        int r = start;
        for (int j = 0; j < NBK; ++j) {
            int c = counts[b * NBK + j];
            counts[b * NBK + j] = r;
            r += c;
        }
        bstart[b] = start;
        if (b == NBUCK - 1) bstart[NBUCK] = start + v;   // = N_EDGES
    }
}

// Pass C: place records (dst<<16|src) at exact offsets; writes are ~contiguous
// runs per (block,bucket) -> low write amplification.
__global__ __launch_bounds__(1024) void place_kernel(
        const int* __restrict__ idx, const int* __restrict__ flag,
        const int* __restrict__ offs, uint* __restrict__ sorted) {
    __shared__ int loc[NBUCK];
    for (int i = threadIdx.x; i < NBUCK; i += 1024)
        loc[i] = offs[i * NBK + blockIdx.x];
    __syncthreads();
    const int f = *flag;
    const int base = blockIdx.x * EPB;
    const int end = min(base + EPB, N_EDGES);
    for (int e = base + threadIdx.x; e < end; e += 1024) {
        int src, dst;
        if (f) { src = idx[2 * e]; dst = idx[2 * N_EDGES + 2 * e]; }
        else   { src = idx[e];     dst = idx[N_EDGES + e]; }
        int pos = atomicAdd(&loc[dst >> 7], 1);
        sorted[pos] = ((uint)dst << 16) | (uint)src;
    }
}

// Pass D: one block per bucket; scatter into the bucket's 12 KB esrc window
// (single-L2-hot) via LDS rank counters; write deg wholesale.
__global__ __launch_bounds__(256) void bin_kernel(
        const uint* __restrict__ sorted, const int* __restrict__ bstart,
        int* __restrict__ deg, ushort* __restrict__ esrc) {
    __shared__ int cnt[128];
    const int b = blockIdx.x;
    if (threadIdx.x < 128) cnt[threadIdx.x] = 0;
    __syncthreads();
    const int s = bstart[b], e = bstart[b + 1];
    for (int i = s + threadIdx.x; i < e; i += 256) {
        uint r = sorted[i];
        int dst = r >> 16, src = r & 0xffff;
        int pos = atomicAdd(&cnt[dst & 127], 1);
        if (pos < CAP) esrc[dst * CAP + pos] = (ushort)src;
    }
    __syncthreads();
    const int node = b * 128 + threadIdx.x;
    if (threadIdx.x < 128 && node < N_NODES) deg[node] = cnt[threadIdx.x];
}

// ---------------------------------------------------------------------------
// Gather + mean over bf16 rows. 2 nodes per wave: half-wave (32 lanes) reads a
// row as uint2 (8B/lane = 256B). 8-edge unroll -> 16 rows in flight per wave.
__global__ __launch_bounds__(256) void gather_mean_kernel(
        const uint2* __restrict__ X2, const int* __restrict__ deg,
        const ushort* __restrict__ esrc, uint2* __restrict__ mean2) {
    const int wave = threadIdx.x >> 6;
    const int lane = threadIdx.x & 63;
    const int node = blockIdx.x * 8 + wave * 2 + (lane >> 5);
    const int l = lane & 31;
    if (node >= N_NODES) return;
    int dg = deg[node];
    if (dg > CAP) dg = CAP;
    const ushort* es = esrc + node * CAP;

    float c0[4] = {0, 0, 0, 0}, c1[4] = {0, 0, 0, 0};
    float c2[4] = {0, 0, 0, 0}, c3[4] = {0, 0, 0, 0};
    int p = 0;
    for (; p + 7 < dg; p += 8) {
        ushort4 sa = *(const ushort4*)(es + p);
        ushort4 sb = *(const ushort4*)(es + p + 4);
        uint2 v0 = X2[(size_t)sa.x * 32 + l];
        uint2 v1 = X2[(size_t)sa.y * 32 + l];
        uint2 v2 = X2[(size_t)sa.z * 32 + l];
        uint2 v3 = X2[(size_t)sa.w * 32 + l];
        uint2 v4 = X2[(size_t)sb.x * 32 + l];
        uint2 v5 = X2[(size_t)sb.y * 32 + l];
        uint2 v6 = X2[(size_t)sb.z * 32 + l];
        uint2 v7 = X2[(size_t)sb.w * 32 + l];
        c0[0] += bf2f(v0.x & 0xffff); c0[1] += bf2f(v0.x >> 16);
        c0[2] += bf2f(v0.y & 0xffff); c0[3] += bf2f(v0.y >> 16);
        c1[0] += bf2f(v1.x & 0xffff); c1[1] += bf2f(v1.x >> 16);
        c1[2] += bf2f(v1.y & 0xffff); c1[3] += bf2f(v1.y >> 16);
        c2[0] += bf2f(v2.x & 0xffff); c2[1] += bf2f(v2.x >> 16);
        c2[2] += bf2f(v2.y & 0xffff); c2[3] += bf2f(v2.y >> 16);
        c3[0] += bf2f(v3.x & 0xffff); c3[1] += bf2f(v3.x >> 16);
        c3[2] += bf2f(v3.y & 0xffff); c3[3] += bf2f(v3.y >> 16);
        c0[0] += bf2f(v4.x & 0xffff); c0[1] += bf2f(v4.x >> 16);
        c0[2] += bf2f(v4.y & 0xffff); c0[3] += bf2f(v4.y >> 16);
        c1[0] += bf2f(v5.x & 0xffff); c1[1] += bf2f(v5.x >> 16);
        c1[2] += bf2f(v5.y & 0xffff); c1[3] += bf2f(v5.y >> 16);
        c2[0] += bf2f(v6.x & 0xffff); c2[1] += bf2f(v6.x >> 16);
        c2[2] += bf2f(v6.y & 0xffff); c2[3] += bf2f(v6.y >> 16);
        c3[0] += bf2f(v7.x & 0xffff); c3[1] += bf2f(v7.x >> 16);
        c3[2] += bf2f(v7.y & 0xffff); c3[3] += bf2f(v7.y >> 16);
    }
    for (; p < dg; ++p) {
        uint2 v = X2[(size_t)es[p] * 32 + l];
        c0[0] += bf2f(v.x & 0xffff); c0[1] += bf2f(v.x >> 16);
        c0[2] += bf2f(v.y & 0xffff); c0[3] += bf2f(v.y >> 16);
    }
    const float inv = 1.0f / (float)max(dg, 1);
    const float m0 = (c0[0] + c1[0] + c2[0] + c3[0]) * inv;
    const float m1 = (c0[1] + c1[1] + c2[1] + c3[1]) * inv;
    const float m2 = (c0[2] + c1[2] + c2[2] + c3[2]) * inv;
    const float m3 = (c0[3] + c1[3] + c2[3] + c3[3]) * inv;
    uint2 m;
    m.x = ((uint)f2bf(m1) << 16) | (uint)f2bf(m0);
    m.y = ((uint)f2bf(m3) << 16) | (uint)f2bf(m2);
    mean2[(size_t)node * 32 + l] = m;
}

// ---------------------------------------------------------------------------
// MFMA GEMM: C = [mean | self](M x 256 bf16) @ Bpack(256 x 128 bf16) + bias,
// fused row-L2-norm + ReLU. BM=64, BN=128; 4 waves. No LDS staging. In-place
// Aself==Y safe: __syncthreads() after K-loop orders A reads before stores.
// Rows >= N_NODES read the adjacent ws buffer (harmless; stores guarded).
template<bool OUT_F32>
__global__ __launch_bounds__(256) void gemm_mfma_kernel(
        const ushort* __restrict__ Amean, const ushort* Aself,
        const ushort* __restrict__ Bpack, const float* __restrict__ bias,
        void* Yout) {
    __shared__ float rs[2][64];
    const int tid = threadIdx.x;
    const int w = tid >> 6, l = tid & 63;
    const int lr = l & 31, lh = l >> 5;
    const int mrow0 = blockIdx.x * 64 + (w & 1) * 32;
    const int t0 = (w >> 1) * 2;

    f32x16 acc0, acc1;
#pragma unroll
    for (int i = 0; i < 16; ++i) { acc0[i] = 0.0f; acc1[i] = 0.0f; }

#pragma unroll
    for (int s = 0; s < 16; ++s) {
        const ushort* Ab = (s < 8) ? Amean : Aself;
        Frag a, b0, b1;
        a.f4  = *(const float4*)(Ab + (size_t)(mrow0 + lr) * 128 + (s & 7) * 16 + lh * 8);
        b0.f4 = *(const float4*)(Bpack + (size_t)(((t0) * 16 + s) * 64 + l) * 8);
        b1.f4 = *(const float4*)(Bpack + (size_t)(((t0 + 1) * 16 + s) * 64 + l) * 8);
        acc0 = __builtin_amdgcn_mfma_f32_32x32x16_bf16(a.h, b0.h, acc0, 0, 0, 0);
        acc1 = __builtin_amdgcn_mfma_f32_32x32x16_bf16(a.h, b1.h, acc1, 0, 0, 0);
    }

    const float bia0 = bias[t0 * 32 + lr];
    const float bia1 = bias[t0 * 32 + 32 + lr];
    float sq[16];
#pragma unroll
    for (int r = 0; r < 16; ++r) {
        float v0 = acc0[r] + bia0;
        float v1 = acc1[r] + bia1;
        acc0[r] = v0; acc1[r] = v1;
        float s_ = v0 * v0 + v1 * v1;
        s_ += __shfl_xor(s_, 1);
        s_ += __shfl_xor(s_, 2);
        s_ += __shfl_xor(s_, 4);
        s_ += __shfl_xor(s_, 8);
        s_ += __shfl_xor(s_, 16);
        sq[r] = s_;
    }
    if (lr == 0) {
#pragma unroll
        for (int r = 0; r < 16; ++r) {
            int rowl = (w & 1) * 32 + (r & 3) + 8 * (r >> 2) + 4 * lh;
            rs[w >> 1][rowl] = sq[r];
        }
    }
    __syncthreads();
#pragma unroll
    for (int r = 0; r < 16; ++r) {
        int rowl = (w & 1) * 32 + (r & 3) + 8 * (r >> 2) + 4 * lh;
        int grow = blockIdx.x * 64 + rowl;
        float tot = rs[0][rowl] + rs[1][rowl];
        float sc = 1.0f / fmaxf(sqrtf(tot), 1e-12f);
        if (grow < N_NODES) {
            float o0 = fmaxf(acc0[r] * sc, 0.0f);
            float o1 = fmaxf(acc1[r] * sc, 0.0f);
            if (OUT_F32) {
                float* Y = (float*)Yout;
                Y[(size_t)grow * 128 + t0 * 32 + lr]      = o0;
                Y[(size_t)grow * 128 + t0 * 32 + 32 + lr] = o1;
            } else {
                ushort* Y = (ushort*)Yout;
                Y[(size_t)grow * 128 + t0 * 32 + lr]      = f2bf(o0);
                Y[(size_t)grow * 128 + t0 * 32 + 32 + lr] = f2bf(o1);
            }
        }
    }
}

extern "C" void kernel_launch(void* const* d_in, const int* in_sizes, int n_in,
                              void* d_out, int out_size, void* d_ws, size_t ws_size,
                              hipStream_t stream) {
    const float* x    = (const float*)d_in[0];
    const int*   idx  = (const int*)d_in[1];
    const float* W1l  = (const float*)d_in[2];
    const float* b1l  = (const float*)d_in[3];
    const float* W1r  = (const float*)d_in[4];
    const float* W2l  = (const float*)d_in[5];
    const float* b2l  = (const float*)d_in[6];
    const float* W2r  = (const float*)d_in[7];
    float* out = (float*)d_out;

    // ws layout (4B-word offsets; total 30.73 MB == R5's proven footprint).
    // counts/bstart/sorted overlay the meanb region (dead until gather1).
    int*    deg    = (int*)d_ws;                        // [50000]
    int*    flag   = deg + N_NODES;                     // [1] (pad to 50016)
    ushort* esrc   = (ushort*)((int*)d_ws + 50016);     // [50000*48] 1.2M words
    uint*   meanb  = (uint*)((int*)d_ws + 1250016);     // [50000*64] 3.2M words
    int*    counts = (int*)meanb;                       // [NBUCK*NBK]=38318
    int*    bstart = (int*)((int*)d_ws + 1290016);      // [NBUCK+1]
    uint*   sorted = (uint*)((int*)d_ws + 1300000);     // [800000]
    uint*   xh     = (uint*)((int*)d_ws + 4450016);     // [50000*64]
    ushort* Bp     = (ushort*)((int*)d_ws + 7650016);   // [2*4096*8] (absorbs
                                                        //  GEMM pad-row reads)

    prep_kernel<<<(N_NODES * 64 + 255) / 256, 256, 0, stream>>>(
        idx, flag, (const float2*)x, xh, W1l, W1r, W2l, W2r, Bp);
    hist_kernel<<<NBK, 1024, 0, stream>>>(idx, flag, counts);
    scan_kernel<<<1, 512, 0, stream>>>(counts, bstart);
    place_kernel<<<NBK, 1024, 0, stream>>>(idx, flag, counts, sorted);
    bin_kernel<<<NBUCK, 256, 0, stream>>>(sorted, bstart, deg, esrc);

    const int gb = (N_NODES + 7) / 8;               // 6250 (8 nodes/block)
    const int mb = (N_NODES + 63) / 64;             // 782

    // layer 1: gather(xh)->meanb; GEMM writes h1 (bf16) in-place over xh
    gather_mean_kernel<<<gb, 256, 0, stream>>>(
        (const uint2*)xh, deg, esrc, (uint2*)meanb);
    gemm_mfma_kernel<false><<<mb, 256, 0, stream>>>(
        (const ushort*)meanb, (const ushort*)xh, Bp, b1l, (void*)xh);
    // layer 2: gather(h1)->meanb; GEMM writes f32 d_out
    gather_mean_kernel<<<gb, 256, 0, stream>>>(
        (const uint2*)xh, deg, esrc, (uint2*)meanb);
    gemm_mfma_kernel<true><<<mb, 256, 0, stream>>>(
        (const ushort*)meanb, (const ushort*)xh, Bp + 4096 * 8, b2l, (void*)out);
}